// Round 12
// baseline (894.893 us; speedup 1.0000x reference)
//
#include <hip/hip_runtime.h>
#include <hip/hip_bf16.h>

#define B_ 32
#define T_ 64
#define H_ 1024
#define G3 3072
#define V_ 32000
#define M_ 2048   // B_*T_
#define NB_SCAN 64
#define NTILE_N 250   // 32000/128

typedef __attribute__((ext_vector_type(8))) short s16x8;
typedef __attribute__((ext_vector_type(4))) float f32x4;
typedef __bf16 bf16x8 __attribute__((ext_vector_type(8)));

__device__ inline unsigned short f2bf(float f) {
    union { float f; unsigned int u; } v; v.f = f;
    unsigned int u = v.u;
    return (unsigned short)((u + 0x7FFFu + ((u >> 16) & 1u)) >> 16);
}

// coherent (LLC-level) ops: sc0 sc1 bypass L1/L2 so cross-XCD producer/consumer
// works without whole-L2 fences. (Proven in the R5 scan protocol.)
__device__ inline s16x8 load_b128_cc(const void* p) {
    s16x8 r;
    asm volatile("global_load_dwordx4 %0, %1, off sc0 sc1" : "=v"(r) : "v"(p));
    return r;
}
__device__ inline unsigned int load_b32_cc(const void* p) {
    unsigned int r;
    asm volatile("global_load_dword %0, %1, off sc0 sc1" : "=v"(r) : "v"(p));
    return r;
}
__device__ inline void store_b32_cc(void* p, unsigned int v) {
    asm volatile("global_store_dword %0, %1, off sc0 sc1" :: "v"(p), "v"(v) : "memory");
}

// ---------------- fused prep: 3 casts + embed_relu + init_h + flag zero ----------------
__global__ __launch_bounds__(256) void prep_all(
    const float* __restrict__ W_ih, const float* __restrict__ W_hh,
    const float* __restrict__ out_W,
    unsigned short* __restrict__ wihb, unsigned short* __restrict__ whhb,
    unsigned short* __restrict__ owb,
    const int* __restrict__ target, const float* __restrict__ emb,
    unsigned short* __restrict__ xb,
    const float* __restrict__ enc_hidden, unsigned short* __restrict__ hb0,
    unsigned int* __restrict__ flg)
{
    int gid = blockIdx.x * 256 + threadIdx.x;
    int gs = gridDim.x * 256;
    const int NW = G3 * H_ / 4;     // 786432 float4s
    const int NO = V_ * H_ / 4;     // 8192000 float4s

    for (int i = gid; i < NW; i += gs) {
        float4 v = *(const float4*)(W_ih + (size_t)i * 4);
        ushort4 o; o.x = f2bf(v.x); o.y = f2bf(v.y); o.z = f2bf(v.z); o.w = f2bf(v.w);
        *(ushort4*)(wihb + (size_t)i * 4) = o;
    }
    for (int i = gid; i < NW; i += gs) {
        float4 v = *(const float4*)(W_hh + (size_t)i * 4);
        ushort4 o; o.x = f2bf(v.x); o.y = f2bf(v.y); o.z = f2bf(v.z); o.w = f2bf(v.w);
        *(ushort4*)(whhb + (size_t)i * 4) = o;
    }
    for (int i = gid; i < NO; i += gs) {
        float4 v = *(const float4*)(out_W + (size_t)i * 4);
        ushort4 o; o.x = f2bf(v.x); o.y = f2bf(v.y); o.z = f2bf(v.z); o.w = f2bf(v.w);
        *(ushort4*)(owb + (size_t)i * 4) = o;
    }
    for (int i = gid; i < M_ * 256; i += gs) {
        int m = i >> 8, k = (i & 255) * 4;
        int b = m >> 6, t = m & 63;
        int tok = (t == 0) ? 1 : target[b * T_ + t - 1];
        float4 v = *(const float4*)(emb + (size_t)tok * H_ + k);
        ushort4 o;
        o.x = f2bf(fmaxf(v.x, 0.f)); o.y = f2bf(fmaxf(v.y, 0.f));
        o.z = f2bf(fmaxf(v.z, 0.f)); o.w = f2bf(fmaxf(v.w, 0.f));
        *(ushort4*)(xb + (size_t)m * H_ + k) = o;
    }
    for (int i = gid; i < B_ * H_; i += gs) hb0[i] = f2bf(enc_hidden[i]);
    for (int i = gid; i < 128; i += gs) flg[i] = 0;
}

// ---------------- GEMM, 3-buffer depth-2 pipeline (counted vmcnt, T3/T4-min) ------------
// Boundary waits vmcnt(4): tile t+1's 4 loads land, tile t+2's 4 stay in flight across
// the raw s_barrier (never drain to 0 in the loop — removes the 2-phase vmcnt(0) stall).
// WAR safe: buffer b is re-staged 2 barriers after its last ds_read; every wave's reads
// are MFMA-consumed (lgkm-waited) before it passes the intervening barrier.
__global__ __launch_bounds__(256) void gemm_bias(
    const unsigned short* __restrict__ A,
    const unsigned short* __restrict__ Bm,
    const float* __restrict__ bias,
    float* __restrict__ C,
    int N, int K)
{
    __shared__ __align__(16) unsigned short As[3 * 4096];  // 3 x [128][32] bf16, linear
    __shared__ __align__(16) unsigned short Bs[3 * 4096];
    int n0 = blockIdx.x * 128, m0 = blockIdx.y * 128;
    int tid = threadIdx.x;
    int lane = tid & 63, wv = tid >> 6;
    int wr = wv >> 1, wc = wv & 1;

    f32x4 acc[4][4] = {};

    int o0 = wv * 2048 + lane * 16;
    int row0 = o0 >> 6, ib0 = (o0 & 63) >> 1;
    int o1 = o0 + 1024;
    int row1 = o1 >> 6, ib1 = (o1 & 63) >> 1;

    auto stage = [&](int buf, int k0) {
        const unsigned short* ga0 = A + (size_t)(m0 + row0) * K + k0 + ib0;
        const unsigned short* gb0 = Bm + (size_t)(n0 + row0) * K + k0 + ib0;
        const unsigned short* ga1 = A + (size_t)(m0 + row1) * K + k0 + ib1;
        const unsigned short* gb1 = Bm + (size_t)(n0 + row1) * K + k0 + ib1;
        unsigned short* la0 = As + buf * 4096 + wv * 1024;
        unsigned short* lb0 = Bs + buf * 4096 + wv * 1024;
        __builtin_amdgcn_global_load_lds((const __attribute__((address_space(1))) void*)ga0,
                                         (__attribute__((address_space(3))) void*)la0, 16, 0, 0);
        __builtin_amdgcn_global_load_lds((const __attribute__((address_space(1))) void*)gb0,
                                         (__attribute__((address_space(3))) void*)lb0, 16, 0, 0);
        __builtin_amdgcn_global_load_lds((const __attribute__((address_space(1))) void*)ga1,
                                         (__attribute__((address_space(3))) void*)(la0 + 512), 16, 0, 0);
        __builtin_amdgcn_global_load_lds((const __attribute__((address_space(1))) void*)gb1,
                                         (__attribute__((address_space(3))) void*)(lb0 + 512), 16, 0, 0);
    };

    int kq = (lane >> 4) * 8;
    int rA = wr * 64 + (lane & 15);
    int rB = wc * 64 + (lane & 15);

    int NT = K >> 5;
    stage(0, 0);
    if (NT > 1) {
        stage(1, 32);
        asm volatile("s_waitcnt vmcnt(4)");      // tile 0 landed; tile 1 in flight
    } else {
        asm volatile("s_waitcnt vmcnt(0)");
    }
    __builtin_amdgcn_s_barrier();
    __builtin_amdgcn_sched_barrier(0);

    int cur = 0;
    for (int t = 0; t < NT; ++t) {
        if (t + 2 < NT) {
            int nb = cur + 2; if (nb >= 3) nb -= 3;
            stage(nb, (t + 2) << 5);
        }
        const unsigned short* ab = As + cur * 4096;
        const unsigned short* bb = Bs + cur * 4096;
        s16x8 af[4], bf[4];
#pragma unroll
        for (int i = 0; i < 4; ++i) {
            af[i] = *(const s16x8*)(ab + (rA + i * 16) * 32 + kq);
            bf[i] = *(const s16x8*)(bb + (rB + i * 16) * 32 + kq);
        }
#pragma unroll
        for (int mf = 0; mf < 4; ++mf)
#pragma unroll
            for (int nf = 0; nf < 4; ++nf)
                acc[mf][nf] = __builtin_amdgcn_mfma_f32_16x16x32_bf16(
                    __builtin_bit_cast(bf16x8, af[mf]),
                    __builtin_bit_cast(bf16x8, bf[nf]),
                    acc[mf][nf], 0, 0, 0);
        if (t + 1 < NT) {
            if (t + 2 < NT) asm volatile("s_waitcnt vmcnt(4)");   // next tile landed; one in flight
            else            asm volatile("s_waitcnt vmcnt(0)");   // pipeline tail
            asm volatile("s_waitcnt lgkmcnt(0)");
            __builtin_amdgcn_s_barrier();
            __builtin_amdgcn_sched_barrier(0);
        }
        cur = (cur == 2) ? 0 : cur + 1;
    }

#pragma unroll
    for (int nf = 0; nf < 4; ++nf) {
        int col = n0 + wc * 64 + nf * 16 + (lane & 15);
        float bv = bias[col];
#pragma unroll
        for (int mf = 0; mf < 4; ++mf) {
            int mbase = m0 + wr * 64 + mf * 16 + (lane >> 4) * 4;
#pragma unroll
            for (int r = 0; r < 4; ++r)
                C[(size_t)(mbase + r) * N + col] = acc[mf][nf][r] + bv;
        }
    }
}

// ---------------- logits GEMM, 3-buffer pipeline + fused softmax partials ----------------
__global__ __launch_bounds__(256) void gemm_logits(
    const unsigned short* __restrict__ A,     // hsb [2048,1024] (row m = b*64+t)
    const unsigned short* __restrict__ Bm,    // owb [32000,1024]
    const float* __restrict__ bias,           // out_b
    float* __restrict__ C,                    // out [2048,32000]
    float* __restrict__ pmax,                 // [2048,250]
    float* __restrict__ psum)                 // [2048,250]
{
    __shared__ __align__(16) unsigned short As[3 * 4096];
    __shared__ __align__(16) unsigned short Bs[3 * 4096];
    __shared__ float spx[2][128], sps[2][128];
    int m0 = blockIdx.x * 128;                 // m fastest
    int ntile = blockIdx.y;
    int n0 = ntile * 128;
    int tid = threadIdx.x;
    int lane = tid & 63, wv = tid >> 6;
    int wr = wv >> 1, wc = wv & 1;

    f32x4 acc[4][4] = {};

    int o0 = wv * 2048 + lane * 16;
    int row0 = o0 >> 6, ib0 = (o0 & 63) >> 1;
    int o1 = o0 + 1024;
    int row1 = o1 >> 6, ib1 = (o1 & 63) >> 1;

    auto stage = [&](int buf, int k0) {
        const unsigned short* ga0 = A + (size_t)(m0 + row0) * H_ + k0 + ib0;
        const unsigned short* gb0 = Bm + (size_t)(n0 + row0) * H_ + k0 + ib0;
        const unsigned short* ga1 = A + (size_t)(m0 + row1) * H_ + k0 + ib1;
        const unsigned short* gb1 = Bm + (size_t)(n0 + row1) * H_ + k0 + ib1;
        unsigned short* la0 = As + buf * 4096 + wv * 1024;
        unsigned short* lb0 = Bs + buf * 4096 + wv * 1024;
        __builtin_amdgcn_global_load_lds((const __attribute__((address_space(1))) void*)ga0,
                                         (__attribute__((address_space(3))) void*)la0, 16, 0, 0);
        __builtin_amdgcn_global_load_lds((const __attribute__((address_space(1))) void*)gb0,
                                         (__attribute__((address_space(3))) void*)lb0, 16, 0, 0);
        __builtin_amdgcn_global_load_lds((const __attribute__((address_space(1))) void*)ga1,
                                         (__attribute__((address_space(3))) void*)(la0 + 512), 16, 0, 0);
        __builtin_amdgcn_global_load_lds((const __attribute__((address_space(1))) void*)gb1,
                                         (__attribute__((address_space(3))) void*)(lb0 + 512), 16, 0, 0);
    };

    int q = lane >> 4, rr2 = lane & 15;
    int kq = q * 8;
    int rA = wr * 64 + rr2;
    int rB = wc * 64 + rr2;

    stage(0, 0);
    stage(1, 32);
    asm volatile("s_waitcnt vmcnt(4)");          // tile 0 landed; tile 1 in flight
    __builtin_amdgcn_s_barrier();
    __builtin_amdgcn_sched_barrier(0);

    int cur = 0;
    for (int t = 0; t < 32; ++t) {
        if (t + 2 < 32) {
            int nb = cur + 2; if (nb >= 3) nb -= 3;
            stage(nb, (t + 2) << 5);
        }
        const unsigned short* ab = As + cur * 4096;
        const unsigned short* bb = Bs + cur * 4096;
        s16x8 af[4], bf[4];
#pragma unroll
        for (int i = 0; i < 4; ++i) {
            af[i] = *(const s16x8*)(ab + (rA + i * 16) * 32 + kq);
            bf[i] = *(const s16x8*)(bb + (rB + i * 16) * 32 + kq);
        }
#pragma unroll
        for (int mf = 0; mf < 4; ++mf)
#pragma unroll
            for (int nf = 0; nf < 4; ++nf)
                acc[mf][nf] = __builtin_amdgcn_mfma_f32_16x16x32_bf16(
                    __builtin_bit_cast(bf16x8, af[mf]),
                    __builtin_bit_cast(bf16x8, bf[nf]),
                    acc[mf][nf], 0, 0, 0);
        if (t + 1 < 32) {
            if (t + 2 < 32) asm volatile("s_waitcnt vmcnt(4)");
            else            asm volatile("s_waitcnt vmcnt(0)");
            asm volatile("s_waitcnt lgkmcnt(0)");
            __builtin_amdgcn_s_barrier();
            __builtin_amdgcn_sched_barrier(0);
        }
        cur = (cur == 2) ? 0 : cur + 1;
    }

    float bv[4];
#pragma unroll
    for (int nf = 0; nf < 4; ++nf) bv[nf] = bias[n0 + wc * 64 + nf * 16 + rr2];

#pragma unroll
    for (int mf = 0; mf < 4; ++mf) {
#pragma unroll
        for (int r = 0; r < 4; ++r) {
            int row_local = wr * 64 + mf * 16 + q * 4 + r;
            float vmax = -1e30f;
#pragma unroll
            for (int nf = 0; nf < 4; ++nf) vmax = fmaxf(vmax, acc[mf][nf][r] + bv[nf]);
#pragma unroll
            for (int o = 1; o < 16; o <<= 1) vmax = fmaxf(vmax, __shfl_xor(vmax, o));
            float vsum = 0.f;
#pragma unroll
            for (int nf = 0; nf < 4; ++nf) vsum += __expf(acc[mf][nf][r] + bv[nf] - vmax);
#pragma unroll
            for (int o = 1; o < 16; o <<= 1) vsum += __shfl_xor(vsum, o);
            if (rr2 == 0) { spx[wc][row_local] = vmax; sps[wc][row_local] = vsum; }
        }
    }

#pragma unroll
    for (int nf = 0; nf < 4; ++nf) {
        int col = n0 + wc * 64 + nf * 16 + rr2;
#pragma unroll
        for (int mf = 0; mf < 4; ++mf) {
            int mbase = m0 + wr * 64 + mf * 16 + q * 4;
#pragma unroll
            for (int r = 0; r < 4; ++r)
                C[(size_t)(mbase + r) * V_ + col] = acc[mf][nf][r] + bv[nf];
        }
    }

    __syncthreads();
    if (wc == 0 && rr2 == 0) {
#pragma unroll
        for (int mf = 0; mf < 4; ++mf)
#pragma unroll
            for (int r = 0; r < 4; ++r) {
                int row_local = wr * 64 + mf * 16 + q * 4 + r;
                float m0v = spx[0][row_local], m1v = spx[1][row_local];
                float Mv = fmaxf(m0v, m1v);
                float Sv = sps[0][row_local] * __expf(m0v - Mv) + sps[1][row_local] * __expf(m1v - Mv);
                pmax[(size_t)(m0 + row_local) * NTILE_N + ntile] = Mv;
                psum[(size_t)(m0 + row_local) * NTILE_N + ntile] = Sv;
            }
    }
}

// ---------------- persistent GRU scan (R9-proven: all-blocks flag barrier) ----------------
// The all-64-flags poll provides BOTH guarantees: (RAW) producers of step t published,
// and (WAR, transitively) every block finished step t, so its reads of buffer W(t-1)
// are complete before anyone overwrites it at step t+1. Do NOT narrow the poll set
// without adding consumer-acks (R10 lesson: fine-grained poll -> ping-pong WAR race).
__global__ __launch_bounds__(256) void gru_scan(
    const unsigned short* __restrict__ Whhb,  // [3072,1024] bf16
    const float* __restrict__ b_hh,           // [3072]
    const float* __restrict__ enc_hidden,     // [32,1024] f32 (initial h)
    const float* __restrict__ xg,             // [2048,3072] f32 (b_ih added)
    unsigned short* __restrict__ hb0, unsigned short* __restrict__ hb1,  // bf16 h ping-pong
    float* __restrict__ hfF,                  // [32,1024] final h f32
    unsigned short* __restrict__ hs,          // [2048,1024] bf16 (row b*64+t)
    unsigned int* __restrict__ flags)         // [64] per-block step flags (pre-zeroed)
{
    __shared__ __align__(16) unsigned short ws_[48 * 1024];   // 96 KB
    __shared__ __align__(16) f32x4 red[2][3][64];             // 6 KB split-K partials

    int tid = threadIdx.x;
    int lane = tid & 63, wave = tid >> 6;
    int rt = wave >> 1, kh = wave & 1;
    int ct = blockIdx.x;

    for (int idx = tid; idx < 48 * 128; idx += 256) {
        int r = idx >> 7, slot = idx & 127;
        int g = r >> 4, jr = r & 15;
        s16x8 v = *(const s16x8*)(Whhb + (size_t)(g * H_ + ct * 16 + jr) * H_ + slot * 8);
        *(s16x8*)(ws_ + r * 1024 + (slot ^ (r & 7)) * 8) = v;
    }
    __syncthreads();

    int rr = lane & 15, q = lane >> 4;
    int col = ct * 16 + rr;
    int xsw = rr & 7;
    int kbase = kh * 512;
    int sbase = kh * 64 + q;
    float br = b_hh[col], bz = b_hh[H_ + col], bn = b_hh[2 * H_ + col];
    int b0 = rt * 16 + q * 4;

    float hold[4];
    float xr[4], xz[4], xn[4];
    if (kh == 1) {
#pragma unroll
        for (int r = 0; r < 4; ++r) {
            hold[r] = enc_hidden[(b0 + r) * H_ + col];
            const float* xrow = xg + ((size_t)(b0 + r) * T_) * G3;   // t = 0
            xr[r] = xrow[col]; xz[r] = xrow[H_ + col]; xn[r] = xrow[2 * H_ + col];
        }
    }

    for (int t = 0; t < T_; ++t) {
        const unsigned short* hbp = (t & 1) ? hb1 : hb0;
        unsigned short*       hbn = (t & 1) ? hb0 : hb1;

        // issue all 16 A-frag loads (coherent, bypass stale L1/L2)
        const unsigned short* ha = hbp + (size_t)(rt * 16 + rr) * H_ + kbase + q * 8;
        s16x8 af[16];
#pragma unroll
        for (int i = 0; i < 16; ++i) af[i] = load_b128_cc(ha + i * 32);

        f32x4 accr, accz, accn;
        if (kh == 1) {
            accr = (f32x4){br, br, br, br};
            accz = (f32x4){bz, bz, bz, bz};
            accn = (f32x4){bn, bn, bn, bn};
        } else {
            accr = (f32x4){0.f, 0.f, 0.f, 0.f};
            accz = accr; accn = accr;
        }

        asm volatile("s_waitcnt vmcnt(0)");
        __builtin_amdgcn_sched_barrier(0);

#pragma unroll
        for (int kk = 0; kk < 16; ++kk) {
            int so = ((sbase + kk * 4) ^ xsw) * 8;
            s16x8 fr = *(const s16x8*)(ws_ + rr * 1024 + so);
            s16x8 fz = *(const s16x8*)(ws_ + (16 + rr) * 1024 + so);
            s16x8 fn = *(const s16x8*)(ws_ + (32 + rr) * 1024 + so);
            bf16x8 a = __builtin_bit_cast(bf16x8, af[kk]);
            accr = __builtin_amdgcn_mfma_f32_16x16x32_bf16(a, __builtin_bit_cast(bf16x8, fr), accr, 0, 0, 0);
            accz = __builtin_amdgcn_mfma_f32_16x16x32_bf16(a, __builtin_bit_cast(bf16x8, fz), accz, 0, 0, 0);
            accn = __builtin_amdgcn_mfma_f32_16x16x32_bf16(a, __builtin_bit_cast(bf16x8, fn), accn, 0, 0, 0);
        }

        if (kh == 0) {
            red[rt][0][lane] = accr; red[rt][1][lane] = accz; red[rt][2][lane] = accn;
        }
        __syncthreads();
        if (kh == 1) {
            accr += red[rt][0][lane]; accz += red[rt][1][lane]; accn += red[rt][2][lane];
            unsigned int hpk[4];
#pragma unroll
            for (int r = 0; r < 4; ++r) {
                float rg = 1.f / (1.f + __expf(-(xr[r] + accr[r])));
                float zg = 1.f / (1.f + __expf(-(xz[r] + accz[r])));
                float ng = tanhf(xn[r] + rg * accn[r]);
                float hnew = (1.f - zg) * ng + zg * hold[r];
                hold[r] = hnew;                       // register carry for next step
                hpk[r] = f2bf(hnew);
            }
#pragma unroll
            for (int r = 0; r < 4; ++r) {
                unsigned int other = __shfl_xor((int)hpk[r], 1);
                if ((rr & 1) == 0) {
                    unsigned int pk = hpk[r] | (other << 16);
                    store_b32_cc(hbn + (size_t)(b0 + r) * H_ + col, pk);                    // coherent
                    *(unsigned int*)(hs + ((size_t)(b0 + r) * T_ + t) * H_ + col) = pk;    // plain
                }
            }
            if (t == T_ - 1) {
#pragma unroll
                for (int r = 0; r < 4; ++r) hfF[(b0 + r) * H_ + col] = hold[r];
            }
            asm volatile("s_waitcnt vmcnt(0)" ::: "memory");   // h stores drained before arrival
        }

        if (t < T_ - 1) {
            __syncthreads();
            if (tid == 0) store_b32_cc(flags + ct, (unsigned int)(t + 1));
            // xg prefetch for step t+1 (off the critical chain; issued before poll)
            if (kh == 1) {
#pragma unroll
                for (int r = 0; r < 4; ++r) {
                    const float* xrow = xg + ((size_t)(b0 + r) * T_ + (t + 1)) * G3;
                    xr[r] = xrow[col]; xz[r] = xrow[H_ + col]; xn[r] = xrow[2 * H_ + col];
                }
                __builtin_amdgcn_sched_barrier(0);
            }
            unsigned int tgt = (unsigned int)(t + 1);
            while (true) {
                unsigned int f = load_b32_cc(flags + lane);
                asm volatile("s_waitcnt vmcnt(0)");
                if (__all(f >= tgt)) break;
                __builtin_amdgcn_s_sleep(1);
            }
            __builtin_amdgcn_sched_barrier(0);
        }
    }
}

// ---------------- lse finalize + subtract + h-tail copy ----------------
__global__ __launch_bounds__(256) void lse_sub_copy(
    float* __restrict__ out,
    const float* __restrict__ pmax, const float* __restrict__ psum,
    const float* __restrict__ hfF)
{
    int m = blockIdx.x;
    int tid = threadIdx.x;
    __shared__ float sm[4], ssum[4];

    // blocks 0..31 also copy the final-h tail (one float4 per thread)
    if (m < B_) {
        float4 v = *(const float4*)(hfF + m * H_ + tid * 4);
        *(float4*)(out + (size_t)M_ * V_ + m * H_ + tid * 4) = v;
    }

    float M = -1e30f, S = 0.f;
    for (int i = tid; i < NTILE_N; i += 256) {
        float pm_ = pmax[(size_t)m * NTILE_N + i];
        float ps_ = psum[(size_t)m * NTILE_N + i];
        float nm = fmaxf(M, pm_);
        S = S * __expf(M - nm) + ps_ * __expf(pm_ - nm);
        M = nm;
    }
    for (int o = 32; o > 0; o >>= 1) {
        float om = __shfl_xor(M, o), os = __shfl_xor(S, o);
        float nm = fmaxf(M, om);
        S = S * __expf(M - nm) + os * __expf(om - nm);
        M = nm;
    }
    int wv = tid >> 6, lane = tid & 63;
    if (lane == 0) { sm[wv] = M; ssum[wv] = S; }
    __syncthreads();
    float fm = fmaxf(fmaxf(sm[0], sm[1]), fmaxf(sm[2], sm[3]));
    float fs = ssum[0] * __expf(sm[0] - fm) + ssum[1] * __expf(sm[1] - fm)
             + ssum[2] * __expf(sm[2] - fm) + ssum[3] * __expf(sm[3] - fm);
    float lse = fm + __logf(fs);

    float* row = out + (size_t)m * V_;
    for (int i = tid * 4; i < V_; i += 1024) {
        float4 v = *(const float4*)(row + i);
        v.x -= lse; v.y -= lse; v.z -= lse; v.w -= lse;
        *(float4*)(row + i) = v;
    }
}

extern "C" void kernel_launch(void* const* d_in, const int* in_sizes, int n_in,
                              void* d_out, int out_size, void* d_ws, size_t ws_size,
                              hipStream_t stream) {
    const float* enc_hidden = (const float*)d_in[1];
    const int*   target     = (const int*)d_in[2];
    const float* embedding  = (const float*)d_in[3];
    const float* W_ih       = (const float*)d_in[4];
    const float* W_hh       = (const float*)d_in[5];
    const float* b_ih       = (const float*)d_in[6];
    const float* b_hh       = (const float*)d_in[7];
    const float* out_W      = (const float*)d_in[8];
    const float* out_b      = (const float*)d_in[9];
    float* out = (float*)d_out;

    char* ws = (char*)d_ws;
    float*          xg   = (float*)(ws);                         // [2048,3072] f32   25,165,824
    unsigned short* xb   = (unsigned short*)(ws + 25165824);     // [2048,1024] bf16   4,194,304 (reused as pm after xg-GEMM)
    unsigned short* hsb  = (unsigned short*)(ws + 29360128);     // [2048,1024] bf16   4,194,304
    unsigned short* wihb = (unsigned short*)(ws + 33554432);     // 6,291,456
    unsigned short* whhb = (unsigned short*)(ws + 39845888);     // 6,291,456
    unsigned short* owb  = (unsigned short*)(ws + 46137344);     // 65,536,000
    float*          hfF  = (float*)(ws + 111673344);             // 131,072
    unsigned short* hb0  = (unsigned short*)(ws + 111804416);    // 65,536
    unsigned short* hb1  = (unsigned short*)(ws + 111869952);    // 65,536
    unsigned int*   flg  = (unsigned int*)(ws + 111935488);      // 512
    // pm buffers reuse the xb region (xb dead after the xg GEMM): 2 x 2,048,000 B
    float*          pmx  = (float*)(ws + 25165824);
    float*          psm  = (float*)(ws + 25165824 + 2048000);

    // 1. fused prep (casts + embed + init_h + flag zero)
    prep_all<<<2048, 256, 0, stream>>>(W_ih, W_hh, out_W, wihb, whhb, owb,
                                       target, embedding, xb, enc_hidden, hb0, flg);

    // 2. xg = relu(emb) @ W_ih^T + b_ih
    gemm_bias<<<dim3(G3 / 128, M_ / 128), 256, 0, stream>>>(xb, wihb, b_ih, xg, G3, H_);

    // 3. persistent GRU scan (all-blocks flag barrier; final h -> hfF)
    {
        void* args[] = { (void*)&whhb, (void*)&b_hh, (void*)&enc_hidden, (void*)&xg,
                         (void*)&hb0, (void*)&hb1, (void*)&hfF, (void*)&hsb, (void*)&flg };
        hipLaunchCooperativeKernel((const void*)gru_scan, dim3(NB_SCAN), dim3(256), args, 0, stream);
    }

    // 4. logits = hs @ out_W^T + out_b (+ fused softmax partials)
    gemm_logits<<<dim3(M_ / 128, NTILE_N), 256, 0, stream>>>(hsb, owb, out_b, out, pmx, psm);

    // 5. lse finalize + subtract + h tail copy
    lse_sub_copy<<<M_, 256, 0, stream>>>(out, pmx, psm, hfF);
}

// Round 13
// 889.635 us; speedup vs baseline: 1.0059x; 1.0059x over previous
//
#include <hip/hip_runtime.h>
#include <hip/hip_bf16.h>

#define B_ 32
#define T_ 64
#define H_ 1024
#define G3 3072
#define V_ 32000
#define M_ 2048   // B_*T_
#define NB_SCAN 64
#define NTILE_N 250   // 32000/128

typedef __attribute__((ext_vector_type(8))) short s16x8;
typedef __attribute__((ext_vector_type(4))) float f32x4;
typedef __bf16 bf16x8 __attribute__((ext_vector_type(8)));

__device__ inline unsigned short f2bf(float f) {
    union { float f; unsigned int u; } v; v.f = f;
    unsigned int u = v.u;
    return (unsigned short)((u + 0x7FFFu + ((u >> 16) & 1u)) >> 16);
}

// coherent (LLC-level) ops: sc0 sc1 bypass L1/L2 so cross-XCD producer/consumer
// works without whole-L2 fences. (Proven in the R5 scan protocol.)
__device__ inline s16x8 load_b128_cc(const void* p) {
    s16x8 r;
    asm volatile("global_load_dwordx4 %0, %1, off sc0 sc1" : "=v"(r) : "v"(p));
    return r;
}
__device__ inline unsigned int load_b32_cc(const void* p) {
    unsigned int r;
    asm volatile("global_load_dword %0, %1, off sc0 sc1" : "=v"(r) : "v"(p));
    return r;
}
__device__ inline void store_b32_cc(void* p, unsigned int v) {
    asm volatile("global_store_dword %0, %1, off sc0 sc1" :: "v"(p), "v"(v) : "memory");
}

// ---------------- fused prep: 3 casts + embed_relu + init_h + flag zero ----------------
__global__ __launch_bounds__(256) void prep_all(
    const float* __restrict__ W_ih, const float* __restrict__ W_hh,
    const float* __restrict__ out_W,
    unsigned short* __restrict__ wihb, unsigned short* __restrict__ whhb,
    unsigned short* __restrict__ owb,
    const int* __restrict__ target, const float* __restrict__ emb,
    unsigned short* __restrict__ xb,
    const float* __restrict__ enc_hidden, unsigned short* __restrict__ hb0,
    unsigned int* __restrict__ flg)
{
    int gid = blockIdx.x * 256 + threadIdx.x;
    int gs = gridDim.x * 256;
    const int NW = G3 * H_ / 4;     // 786432 float4s
    const int NO = V_ * H_ / 4;     // 8192000 float4s

    for (int i = gid; i < NW; i += gs) {
        float4 v = *(const float4*)(W_ih + (size_t)i * 4);
        ushort4 o; o.x = f2bf(v.x); o.y = f2bf(v.y); o.z = f2bf(v.z); o.w = f2bf(v.w);
        *(ushort4*)(wihb + (size_t)i * 4) = o;
    }
    for (int i = gid; i < NW; i += gs) {
        float4 v = *(const float4*)(W_hh + (size_t)i * 4);
        ushort4 o; o.x = f2bf(v.x); o.y = f2bf(v.y); o.z = f2bf(v.z); o.w = f2bf(v.w);
        *(ushort4*)(whhb + (size_t)i * 4) = o;
    }
    for (int i = gid; i < NO; i += gs) {
        float4 v = *(const float4*)(out_W + (size_t)i * 4);
        ushort4 o; o.x = f2bf(v.x); o.y = f2bf(v.y); o.z = f2bf(v.z); o.w = f2bf(v.w);
        *(ushort4*)(owb + (size_t)i * 4) = o;
    }
    for (int i = gid; i < M_ * 256; i += gs) {
        int m = i >> 8, k = (i & 255) * 4;
        int b = m >> 6, t = m & 63;
        int tok = (t == 0) ? 1 : target[b * T_ + t - 1];
        float4 v = *(const float4*)(emb + (size_t)tok * H_ + k);
        ushort4 o;
        o.x = f2bf(fmaxf(v.x, 0.f)); o.y = f2bf(fmaxf(v.y, 0.f));
        o.z = f2bf(fmaxf(v.z, 0.f)); o.w = f2bf(fmaxf(v.w, 0.f));
        *(ushort4*)(xb + (size_t)m * H_ + k) = o;
    }
    for (int i = gid; i < B_ * H_; i += gs) hb0[i] = f2bf(enc_hidden[i]);
    for (int i = gid; i < 128; i += gs) flg[i] = 0;
}

// ---------------- GEMM, 3-buffer depth-2 pipeline + LDS bank swizzle -------------------
// Bank fix (R13): lanes 0-15 read rows 0..15 at the SAME 16B slot of a 64B row ->
// 2 four-bank clusters serve 16 lanes = ~8-way conflict (LDS-read-bound, m136).
// Swizzle slot' = slot ^ ((row>>1)&3): 8 lanes per cluster = the 8-cycle floor.
// global_load_lds writes linearly, so the GLOBAL source is inverse-permuted (XOR
// involution, rule #21) and the ds_read address carries the same XOR.
__global__ __launch_bounds__(256) void gemm_bias(
    const unsigned short* __restrict__ A,
    const unsigned short* __restrict__ Bm,
    const float* __restrict__ bias,
    float* __restrict__ C,
    int N, int K)
{
    __shared__ __align__(16) unsigned short As[3 * 4096];  // 3 x [128][32] bf16, linear
    __shared__ __align__(16) unsigned short Bs[3 * 4096];
    int n0 = blockIdx.x * 128, m0 = blockIdx.y * 128;
    int tid = threadIdx.x;
    int lane = tid & 63, wv = tid >> 6;
    int wr = wv >> 1, wc = wv & 1;

    f32x4 acc[4][4] = {};

    int o0 = wv * 2048 + lane * 16;
    int row0 = o0 >> 6, sl0 = (o0 >> 4) & 3;
    int ib0 = (sl0 ^ ((row0 >> 1) & 3)) * 8;          // swizzled global k-slot
    int o1 = o0 + 1024;
    int row1 = o1 >> 6, sl1 = (o1 >> 4) & 3;
    int ib1 = (sl1 ^ ((row1 >> 1) & 3)) * 8;

    auto stage = [&](int buf, int k0) {
        const unsigned short* ga0 = A + (size_t)(m0 + row0) * K + k0 + ib0;
        const unsigned short* gb0 = Bm + (size_t)(n0 + row0) * K + k0 + ib0;
        const unsigned short* ga1 = A + (size_t)(m0 + row1) * K + k0 + ib1;
        const unsigned short* gb1 = Bm + (size_t)(n0 + row1) * K + k0 + ib1;
        unsigned short* la0 = As + buf * 4096 + wv * 1024;
        unsigned short* lb0 = Bs + buf * 4096 + wv * 1024;
        __builtin_amdgcn_global_load_lds((const __attribute__((address_space(1))) void*)ga0,
                                         (__attribute__((address_space(3))) void*)la0, 16, 0, 0);
        __builtin_amdgcn_global_load_lds((const __attribute__((address_space(1))) void*)gb0,
                                         (__attribute__((address_space(3))) void*)lb0, 16, 0, 0);
        __builtin_amdgcn_global_load_lds((const __attribute__((address_space(1))) void*)ga1,
                                         (__attribute__((address_space(3))) void*)(la0 + 512), 16, 0, 0);
        __builtin_amdgcn_global_load_lds((const __attribute__((address_space(1))) void*)gb1,
                                         (__attribute__((address_space(3))) void*)(lb0 + 512), 16, 0, 0);
    };

    int rr2 = lane & 15, q = lane >> 4;
    int kqs = ((q ^ ((rr2 >> 1) & 3)) * 8);           // swizzled read slot (same for A & B:
    int rA = wr * 64 + rr2;                            //  (row>>1)&3 is frag-invariant, = (rr2>>1)&3)
    int rB = wc * 64 + rr2;

    int NT = K >> 5;
    stage(0, 0);
    if (NT > 1) {
        stage(1, 32);
        asm volatile("s_waitcnt vmcnt(4)");      // tile 0 landed; tile 1 in flight
    } else {
        asm volatile("s_waitcnt vmcnt(0)");
    }
    __builtin_amdgcn_s_barrier();
    __builtin_amdgcn_sched_barrier(0);

    int cur = 0;
    for (int t = 0; t < NT; ++t) {
        if (t + 2 < NT) {
            int nb = cur + 2; if (nb >= 3) nb -= 3;
            stage(nb, (t + 2) << 5);
        }
        const unsigned short* ab = As + cur * 4096;
        const unsigned short* bb = Bs + cur * 4096;
        s16x8 af[4], bf[4];
#pragma unroll
        for (int i = 0; i < 4; ++i) {
            af[i] = *(const s16x8*)(ab + (rA + i * 16) * 32 + kqs);
            bf[i] = *(const s16x8*)(bb + (rB + i * 16) * 32 + kqs);
        }
#pragma unroll
        for (int mf = 0; mf < 4; ++mf)
#pragma unroll
            for (int nf = 0; nf < 4; ++nf)
                acc[mf][nf] = __builtin_amdgcn_mfma_f32_16x16x32_bf16(
                    __builtin_bit_cast(bf16x8, af[mf]),
                    __builtin_bit_cast(bf16x8, bf[nf]),
                    acc[mf][nf], 0, 0, 0);
        if (t + 1 < NT) {
            if (t + 2 < NT) asm volatile("s_waitcnt vmcnt(4)");   // next tile landed; one in flight
            else            asm volatile("s_waitcnt vmcnt(0)");   // pipeline tail
            asm volatile("s_waitcnt lgkmcnt(0)");
            __builtin_amdgcn_s_barrier();
            __builtin_amdgcn_sched_barrier(0);
        }
        cur = (cur == 2) ? 0 : cur + 1;
    }

#pragma unroll
    for (int nf = 0; nf < 4; ++nf) {
        int col = n0 + wc * 64 + nf * 16 + rr2;
        float bv = bias[col];
#pragma unroll
        for (int mf = 0; mf < 4; ++mf) {
            int mbase = m0 + wr * 64 + mf * 16 + q * 4;
#pragma unroll
            for (int r = 0; r < 4; ++r)
                C[(size_t)(mbase + r) * N + col] = acc[mf][nf][r] + bv;
        }
    }
}

// ---------------- logits GEMM, 3-buffer pipeline + swizzle + fused softmax partials ----
__global__ __launch_bounds__(256) void gemm_logits(
    const unsigned short* __restrict__ A,     // hsb [2048,1024] (row m = b*64+t)
    const unsigned short* __restrict__ Bm,    // owb [32000,1024]
    const float* __restrict__ bias,           // out_b
    float* __restrict__ C,                    // out [2048,32000]
    float* __restrict__ pmax,                 // [2048,250]
    float* __restrict__ psum)                 // [2048,250]
{
    __shared__ __align__(16) unsigned short As[3 * 4096];
    __shared__ __align__(16) unsigned short Bs[3 * 4096];
    __shared__ float spx[2][128], sps[2][128];
    int m0 = blockIdx.x * 128;                 // m fastest
    int ntile = blockIdx.y;
    int n0 = ntile * 128;
    int tid = threadIdx.x;
    int lane = tid & 63, wv = tid >> 6;
    int wr = wv >> 1, wc = wv & 1;

    f32x4 acc[4][4] = {};

    int o0 = wv * 2048 + lane * 16;
    int row0 = o0 >> 6, sl0 = (o0 >> 4) & 3;
    int ib0 = (sl0 ^ ((row0 >> 1) & 3)) * 8;
    int o1 = o0 + 1024;
    int row1 = o1 >> 6, sl1 = (o1 >> 4) & 3;
    int ib1 = (sl1 ^ ((row1 >> 1) & 3)) * 8;

    auto stage = [&](int buf, int k0) {
        const unsigned short* ga0 = A + (size_t)(m0 + row0) * H_ + k0 + ib0;
        const unsigned short* gb0 = Bm + (size_t)(n0 + row0) * H_ + k0 + ib0;
        const unsigned short* ga1 = A + (size_t)(m0 + row1) * H_ + k0 + ib1;
        const unsigned short* gb1 = Bm + (size_t)(n0 + row1) * H_ + k0 + ib1;
        unsigned short* la0 = As + buf * 4096 + wv * 1024;
        unsigned short* lb0 = Bs + buf * 4096 + wv * 1024;
        __builtin_amdgcn_global_load_lds((const __attribute__((address_space(1))) void*)ga0,
                                         (__attribute__((address_space(3))) void*)la0, 16, 0, 0);
        __builtin_amdgcn_global_load_lds((const __attribute__((address_space(1))) void*)gb0,
                                         (__attribute__((address_space(3))) void*)lb0, 16, 0, 0);
        __builtin_amdgcn_global_load_lds((const __attribute__((address_space(1))) void*)ga1,
                                         (__attribute__((address_space(3))) void*)(la0 + 512), 16, 0, 0);
        __builtin_amdgcn_global_load_lds((const __attribute__((address_space(1))) void*)gb1,
                                         (__attribute__((address_space(3))) void*)(lb0 + 512), 16, 0, 0);
    };

    int q = lane >> 4, rr2 = lane & 15;
    int kqs = ((q ^ ((rr2 >> 1) & 3)) * 8);
    int rA = wr * 64 + rr2;
    int rB = wc * 64 + rr2;

    stage(0, 0);
    stage(1, 32);
    asm volatile("s_waitcnt vmcnt(4)");          // tile 0 landed; tile 1 in flight
    __builtin_amdgcn_s_barrier();
    __builtin_amdgcn_sched_barrier(0);

    int cur = 0;
    for (int t = 0; t < 32; ++t) {
        if (t + 2 < 32) {
            int nb = cur + 2; if (nb >= 3) nb -= 3;
            stage(nb, (t + 2) << 5);
        }
        const unsigned short* ab = As + cur * 4096;
        const unsigned short* bb = Bs + cur * 4096;
        s16x8 af[4], bf[4];
#pragma unroll
        for (int i = 0; i < 4; ++i) {
            af[i] = *(const s16x8*)(ab + (rA + i * 16) * 32 + kqs);
            bf[i] = *(const s16x8*)(bb + (rB + i * 16) * 32 + kqs);
        }
#pragma unroll
        for (int mf = 0; mf < 4; ++mf)
#pragma unroll
            for (int nf = 0; nf < 4; ++nf)
                acc[mf][nf] = __builtin_amdgcn_mfma_f32_16x16x32_bf16(
                    __builtin_bit_cast(bf16x8, af[mf]),
                    __builtin_bit_cast(bf16x8, bf[nf]),
                    acc[mf][nf], 0, 0, 0);
        if (t + 1 < 32) {
            if (t + 2 < 32) asm volatile("s_waitcnt vmcnt(4)");
            else            asm volatile("s_waitcnt vmcnt(0)");
            asm volatile("s_waitcnt lgkmcnt(0)");
            __builtin_amdgcn_s_barrier();
            __builtin_amdgcn_sched_barrier(0);
        }
        cur = (cur == 2) ? 0 : cur + 1;
    }

    float bv[4];
#pragma unroll
    for (int nf = 0; nf < 4; ++nf) bv[nf] = bias[n0 + wc * 64 + nf * 16 + rr2];

#pragma unroll
    for (int mf = 0; mf < 4; ++mf) {
#pragma unroll
        for (int r = 0; r < 4; ++r) {
            int row_local = wr * 64 + mf * 16 + q * 4 + r;
            float vmax = -1e30f;
#pragma unroll
            for (int nf = 0; nf < 4; ++nf) vmax = fmaxf(vmax, acc[mf][nf][r] + bv[nf]);
#pragma unroll
            for (int o = 1; o < 16; o <<= 1) vmax = fmaxf(vmax, __shfl_xor(vmax, o));
            float vsum = 0.f;
#pragma unroll
            for (int nf = 0; nf < 4; ++nf) vsum += __expf(acc[mf][nf][r] + bv[nf] - vmax);
#pragma unroll
            for (int o = 1; o < 16; o <<= 1) vsum += __shfl_xor(vsum, o);
            if (rr2 == 0) { spx[wc][row_local] = vmax; sps[wc][row_local] = vsum; }
        }
    }

#pragma unroll
    for (int nf = 0; nf < 4; ++nf) {
        int col = n0 + wc * 64 + nf * 16 + rr2;
#pragma unroll
        for (int mf = 0; mf < 4; ++mf) {
            int mbase = m0 + wr * 64 + mf * 16 + q * 4;
#pragma unroll
            for (int r = 0; r < 4; ++r)
                C[(size_t)(mbase + r) * V_ + col] = acc[mf][nf][r] + bv[nf];
        }
    }

    __syncthreads();
    if (wc == 0 && rr2 == 0) {
#pragma unroll
        for (int mf = 0; mf < 4; ++mf)
#pragma unroll
            for (int r = 0; r < 4; ++r) {
                int row_local = wr * 64 + mf * 16 + q * 4 + r;
                float m0v = spx[0][row_local], m1v = spx[1][row_local];
                float Mv = fmaxf(m0v, m1v);
                float Sv = sps[0][row_local] * __expf(m0v - Mv) + sps[1][row_local] * __expf(m1v - Mv);
                pmax[(size_t)(m0 + row_local) * NTILE_N + ntile] = Mv;
                psum[(size_t)(m0 + row_local) * NTILE_N + ntile] = Sv;
            }
    }
}

// ---------------- persistent GRU scan (R9-proven: all-blocks flag barrier) ----------------
// The all-64-flags poll provides BOTH guarantees: (RAW) producers of step t published,
// and (WAR, transitively) every block finished step t, so its reads of buffer W(t-1)
// are complete before anyone overwrites it at step t+1. Do NOT narrow the poll set
// without adding consumer-acks (R10 lesson: fine-grained poll -> ping-pong WAR race).
__global__ __launch_bounds__(256) void gru_scan(
    const unsigned short* __restrict__ Whhb,  // [3072,1024] bf16
    const float* __restrict__ b_hh,           // [3072]
    const float* __restrict__ enc_hidden,     // [32,1024] f32 (initial h)
    const float* __restrict__ xg,             // [2048,3072] f32 (b_ih added)
    unsigned short* __restrict__ hb0, unsigned short* __restrict__ hb1,  // bf16 h ping-pong
    float* __restrict__ hfF,                  // [32,1024] final h f32
    unsigned short* __restrict__ hs,          // [2048,1024] bf16 (row b*64+t)
    unsigned int* __restrict__ flags)         // [64] per-block step flags (pre-zeroed)
{
    __shared__ __align__(16) unsigned short ws_[48 * 1024];   // 96 KB
    __shared__ __align__(16) f32x4 red[2][3][64];             // 6 KB split-K partials

    int tid = threadIdx.x;
    int lane = tid & 63, wave = tid >> 6;
    int rt = wave >> 1, kh = wave & 1;
    int ct = blockIdx.x;

    for (int idx = tid; idx < 48 * 128; idx += 256) {
        int r = idx >> 7, slot = idx & 127;
        int g = r >> 4, jr = r & 15;
        s16x8 v = *(const s16x8*)(Whhb + (size_t)(g * H_ + ct * 16 + jr) * H_ + slot * 8);
        *(s16x8*)(ws_ + r * 1024 + (slot ^ (r & 7)) * 8) = v;
    }
    __syncthreads();

    int rr = lane & 15, q = lane >> 4;
    int col = ct * 16 + rr;
    int xsw = rr & 7;
    int kbase = kh * 512;
    int sbase = kh * 64 + q;
    float br = b_hh[col], bz = b_hh[H_ + col], bn = b_hh[2 * H_ + col];
    int b0 = rt * 16 + q * 4;

    float hold[4];
    float xr[4], xz[4], xn[4];
    if (kh == 1) {
#pragma unroll
        for (int r = 0; r < 4; ++r) {
            hold[r] = enc_hidden[(b0 + r) * H_ + col];
            const float* xrow = xg + ((size_t)(b0 + r) * T_) * G3;   // t = 0
            xr[r] = xrow[col]; xz[r] = xrow[H_ + col]; xn[r] = xrow[2 * H_ + col];
        }
    }

    for (int t = 0; t < T_; ++t) {
        const unsigned short* hbp = (t & 1) ? hb1 : hb0;
        unsigned short*       hbn = (t & 1) ? hb0 : hb1;

        // issue all 16 A-frag loads (coherent, bypass stale L1/L2)
        const unsigned short* ha = hbp + (size_t)(rt * 16 + rr) * H_ + kbase + q * 8;
        s16x8 af[16];
#pragma unroll
        for (int i = 0; i < 16; ++i) af[i] = load_b128_cc(ha + i * 32);

        f32x4 accr, accz, accn;
        if (kh == 1) {
            accr = (f32x4){br, br, br, br};
            accz = (f32x4){bz, bz, bz, bz};
            accn = (f32x4){bn, bn, bn, bn};
        } else {
            accr = (f32x4){0.f, 0.f, 0.f, 0.f};
            accz = accr; accn = accr;
        }

        asm volatile("s_waitcnt vmcnt(0)");
        __builtin_amdgcn_sched_barrier(0);

#pragma unroll
        for (int kk = 0; kk < 16; ++kk) {
            int so = ((sbase + kk * 4) ^ xsw) * 8;
            s16x8 fr = *(const s16x8*)(ws_ + rr * 1024 + so);
            s16x8 fz = *(const s16x8*)(ws_ + (16 + rr) * 1024 + so);
            s16x8 fn = *(const s16x8*)(ws_ + (32 + rr) * 1024 + so);
            bf16x8 a = __builtin_bit_cast(bf16x8, af[kk]);
            accr = __builtin_amdgcn_mfma_f32_16x16x32_bf16(a, __builtin_bit_cast(bf16x8, fr), accr, 0, 0, 0);
            accz = __builtin_amdgcn_mfma_f32_16x16x32_bf16(a, __builtin_bit_cast(bf16x8, fz), accz, 0, 0, 0);
            accn = __builtin_amdgcn_mfma_f32_16x16x32_bf16(a, __builtin_bit_cast(bf16x8, fn), accn, 0, 0, 0);
        }

        if (kh == 0) {
            red[rt][0][lane] = accr; red[rt][1][lane] = accz; red[rt][2][lane] = accn;
        }
        __syncthreads();
        if (kh == 1) {
            accr += red[rt][0][lane]; accz += red[rt][1][lane]; accn += red[rt][2][lane];
            unsigned int hpk[4];
#pragma unroll
            for (int r = 0; r < 4; ++r) {
                float rg = 1.f / (1.f + __expf(-(xr[r] + accr[r])));
                float zg = 1.f / (1.f + __expf(-(xz[r] + accz[r])));
                float ng = tanhf(xn[r] + rg * accn[r]);
                float hnew = (1.f - zg) * ng + zg * hold[r];
                hold[r] = hnew;                       // register carry for next step
                hpk[r] = f2bf(hnew);
            }
#pragma unroll
            for (int r = 0; r < 4; ++r) {
                unsigned int other = __shfl_xor((int)hpk[r], 1);
                if ((rr & 1) == 0) {
                    unsigned int pk = hpk[r] | (other << 16);
                    store_b32_cc(hbn + (size_t)(b0 + r) * H_ + col, pk);                    // coherent
                    *(unsigned int*)(hs + ((size_t)(b0 + r) * T_ + t) * H_ + col) = pk;    // plain
                }
            }
            if (t == T_ - 1) {
#pragma unroll
                for (int r = 0; r < 4; ++r) hfF[(b0 + r) * H_ + col] = hold[r];
            }
            asm volatile("s_waitcnt vmcnt(0)" ::: "memory");   // h stores drained before arrival
        }

        if (t < T_ - 1) {
            __syncthreads();
            if (tid == 0) store_b32_cc(flags + ct, (unsigned int)(t + 1));
            // xg prefetch for step t+1 (off the critical chain; issued before poll)
            if (kh == 1) {
#pragma unroll
                for (int r = 0; r < 4; ++r) {
                    const float* xrow = xg + ((size_t)(b0 + r) * T_ + (t + 1)) * G3;
                    xr[r] = xrow[col]; xz[r] = xrow[H_ + col]; xn[r] = xrow[2 * H_ + col];
                }
                __builtin_amdgcn_sched_barrier(0);
            }
            unsigned int tgt = (unsigned int)(t + 1);
            while (true) {
                unsigned int f = load_b32_cc(flags + lane);
                asm volatile("s_waitcnt vmcnt(0)");
                if (__all(f >= tgt)) break;
                __builtin_amdgcn_s_sleep(1);
            }
            __builtin_amdgcn_sched_barrier(0);
        }
    }
}

// ---------------- lse finalize + subtract + h-tail copy ----------------
__global__ __launch_bounds__(256) void lse_sub_copy(
    float* __restrict__ out,
    const float* __restrict__ pmax, const float* __restrict__ psum,
    const float* __restrict__ hfF)
{
    int m = blockIdx.x;
    int tid = threadIdx.x;
    __shared__ float sm[4], ssum[4];

    // blocks 0..31 also copy the final-h tail (one float4 per thread)
    if (m < B_) {
        float4 v = *(const float4*)(hfF + m * H_ + tid * 4);
        *(float4*)(out + (size_t)M_ * V_ + m * H_ + tid * 4) = v;
    }

    float M = -1e30f, S = 0.f;
    for (int i = tid; i < NTILE_N; i += 256) {
        float pm_ = pmax[(size_t)m * NTILE_N + i];
        float ps_ = psum[(size_t)m * NTILE_N + i];
        float nm = fmaxf(M, pm_);
        S = S * __expf(M - nm) + ps_ * __expf(pm_ - nm);
        M = nm;
    }
    for (int o = 32; o > 0; o >>= 1) {
        float om = __shfl_xor(M, o), os = __shfl_xor(S, o);
        float nm = fmaxf(M, om);
        S = S * __expf(M - nm) + os * __expf(om - nm);
        M = nm;
    }
    int wv = tid >> 6, lane = tid & 63;
    if (lane == 0) { sm[wv] = M; ssum[wv] = S; }
    __syncthreads();
    float fm = fmaxf(fmaxf(sm[0], sm[1]), fmaxf(sm[2], sm[3]));
    float fs = ssum[0] * __expf(sm[0] - fm) + ssum[1] * __expf(sm[1] - fm)
             + ssum[2] * __expf(sm[2] - fm) + ssum[3] * __expf(sm[3] - fm);
    float lse = fm + __logf(fs);

    float* row = out + (size_t)m * V_;
    for (int i = tid * 4; i < V_; i += 1024) {
        float4 v = *(const float4*)(row + i);
        v.x -= lse; v.y -= lse; v.z -= lse; v.w -= lse;
        *(float4*)(row + i) = v;
    }
}

extern "C" void kernel_launch(void* const* d_in, const int* in_sizes, int n_in,
                              void* d_out, int out_size, void* d_ws, size_t ws_size,
                              hipStream_t stream) {
    const float* enc_hidden = (const float*)d_in[1];
    const int*   target     = (const int*)d_in[2];
    const float* embedding  = (const float*)d_in[3];
    const float* W_ih       = (const float*)d_in[4];
    const float* W_hh       = (const float*)d_in[5];
    const float* b_ih       = (const float*)d_in[6];
    const float* b_hh       = (const float*)d_in[7];
    const float* out_W      = (const float*)d_in[8];
    const float* out_b      = (const float*)d_in[9];
    float* out = (float*)d_out;

    char* ws = (char*)d_ws;
    float*          xg   = (float*)(ws);                         // [2048,3072] f32   25,165,824
    unsigned short* xb   = (unsigned short*)(ws + 25165824);     // [2048,1024] bf16   4,194,304 (reused as pm after xg-GEMM)
    unsigned short* hsb  = (unsigned short*)(ws + 29360128);     // [2048,1024] bf16   4,194,304
    unsigned short* wihb = (unsigned short*)(ws + 33554432);     // 6,291,456
    unsigned short* whhb = (unsigned short*)(ws + 39845888);     // 6,291,456
    unsigned short* owb  = (unsigned short*)(ws + 46137344);     // 65,536,000
    float*          hfF  = (float*)(ws + 111673344);             // 131,072
    unsigned short* hb0  = (unsigned short*)(ws + 111804416);    // 65,536
    unsigned short* hb1  = (unsigned short*)(ws + 111869952);    // 65,536
    unsigned int*   flg  = (unsigned int*)(ws + 111935488);      // 512
    // pm buffers reuse the xb region (xb dead after the xg GEMM): 2 x 2,048,000 B
    float*          pmx  = (float*)(ws + 25165824);
    float*          psm  = (float*)(ws + 25165824 + 2048000);

    // 1. fused prep (casts + embed + init_h + flag zero)
    prep_all<<<2048, 256, 0, stream>>>(W_ih, W_hh, out_W, wihb, whhb, owb,
                                       target, embedding, xb, enc_hidden, hb0, flg);

    // 2. xg = relu(emb) @ W_ih^T + b_ih
    gemm_bias<<<dim3(G3 / 128, M_ / 128), 256, 0, stream>>>(xb, wihb, b_ih, xg, G3, H_);

    // 3. persistent GRU scan (all-blocks flag barrier; final h -> hfF)
    {
        void* args[] = { (void*)&whhb, (void*)&b_hh, (void*)&enc_hidden, (void*)&xg,
                         (void*)&hb0, (void*)&hb1, (void*)&hfF, (void*)&hsb, (void*)&flg };
        hipLaunchCooperativeKernel((const void*)gru_scan, dim3(NB_SCAN), dim3(256), args, 0, stream);
    }

    // 4. logits = hs @ out_W^T + out_b (+ fused softmax partials)
    gemm_logits<<<dim3(M_ / 128, NTILE_N), 256, 0, stream>>>(hsb, owb, out_b, out, pmx, psm);

    // 5. lse finalize + subtract + h tail copy
    lse_sub_copy<<<M_, 256, 0, stream>>>(out, pmx, psm, hfF);
}

// Round 16
// 824.622 us; speedup vs baseline: 1.0852x; 1.0788x over previous
//
#include <hip/hip_runtime.h>
#include <hip/hip_bf16.h>

#define B_ 32
#define T_ 64
#define H_ 1024
#define G3 3072
#define V_ 32000
#define M_ 2048   // B_*T_
#define NB_SCAN 64
#define NKT 16    // K-tiles of 64 in logits GEMM
#define NTN2 125  // 32000/256

typedef __attribute__((ext_vector_type(8))) short s16x8;
typedef __attribute__((ext_vector_type(4))) float f32x4;
typedef __bf16 bf16x8 __attribute__((ext_vector_type(8)));

__device__ inline unsigned short f2bf(float f) {
    union { float f; unsigned int u; } v; v.f = f;
    unsigned int u = v.u;
    return (unsigned short)((u + 0x7FFFu + ((u >> 16) & 1u)) >> 16);
}

__device__ inline f32x4 mfma16(s16x8 a, s16x8 b, f32x4 c) {
    return __builtin_amdgcn_mfma_f32_16x16x32_bf16(
        __builtin_bit_cast(bf16x8, a), __builtin_bit_cast(bf16x8, b), c, 0, 0, 0);
}

// coherent (LLC-level) ops: sc0 sc1 bypass L1/L2 (R5-proven scan protocol)
__device__ inline s16x8 load_b128_cc(const void* p) {
    s16x8 r;
    asm volatile("global_load_dwordx4 %0, %1, off sc0 sc1" : "=v"(r) : "v"(p));
    return r;
}
__device__ inline unsigned int load_b32_cc(const void* p) {
    unsigned int r;
    asm volatile("global_load_dword %0, %1, off sc0 sc1" : "=v"(r) : "v"(p));
    return r;
}
__device__ inline void store_b32_cc(void* p, unsigned int v) {
    asm volatile("global_store_dword %0, %1, off sc0 sc1" :: "v"(p), "v"(v) : "memory");
}

// ---------------- fused prep: 3 casts + embed_relu + init_h + flag zero ----------------
__global__ __launch_bounds__(256) void prep_all(
    const float* __restrict__ W_ih, const float* __restrict__ W_hh,
    const float* __restrict__ out_W,
    unsigned short* __restrict__ wihb, unsigned short* __restrict__ whhb,
    unsigned short* __restrict__ owb,
    const int* __restrict__ target, const float* __restrict__ emb,
    unsigned short* __restrict__ xb,
    const float* __restrict__ enc_hidden, unsigned short* __restrict__ hb0,
    unsigned int* __restrict__ flg)
{
    int gid = blockIdx.x * 256 + threadIdx.x;
    int gs = gridDim.x * 256;
    const int NW = G3 * H_ / 4;
    const int NO = V_ * H_ / 4;

    for (int i = gid; i < NW; i += gs) {
        float4 v = *(const float4*)(W_ih + (size_t)i * 4);
        ushort4 o; o.x = f2bf(v.x); o.y = f2bf(v.y); o.z = f2bf(v.z); o.w = f2bf(v.w);
        *(ushort4*)(wihb + (size_t)i * 4) = o;
    }
    for (int i = gid; i < NW; i += gs) {
        float4 v = *(const float4*)(W_hh + (size_t)i * 4);
        ushort4 o; o.x = f2bf(v.x); o.y = f2bf(v.y); o.z = f2bf(v.z); o.w = f2bf(v.w);
        *(ushort4*)(whhb + (size_t)i * 4) = o;
    }
    for (int i = gid; i < NO; i += gs) {
        float4 v = *(const float4*)(out_W + (size_t)i * 4);
        ushort4 o; o.x = f2bf(v.x); o.y = f2bf(v.y); o.z = f2bf(v.z); o.w = f2bf(v.w);
        *(ushort4*)(owb + (size_t)i * 4) = o;
    }
    for (int i = gid; i < M_ * 256; i += gs) {
        int m = i >> 8, k = (i & 255) * 4;
        int b = m >> 6, t = m & 63;
        int tok = (t == 0) ? 1 : target[b * T_ + t - 1];
        float4 v = *(const float4*)(emb + (size_t)tok * H_ + k);
        ushort4 o;
        o.x = f2bf(fmaxf(v.x, 0.f)); o.y = f2bf(fmaxf(v.y, 0.f));
        o.z = f2bf(fmaxf(v.z, 0.f)); o.w = f2bf(fmaxf(v.w, 0.f));
        *(ushort4*)(xb + (size_t)m * H_ + k) = o;
    }
    for (int i = gid; i < B_ * H_; i += gs) hb0[i] = f2bf(enc_hidden[i]);
    for (int i = gid; i < 128; i += gs) flg[i] = 0;
}

// ---------------- xg GEMM (R13-green): 128x128, 3-buffer, swizzled ----------------
__global__ __launch_bounds__(256) void gemm_bias(
    const unsigned short* __restrict__ A,
    const unsigned short* __restrict__ Bm,
    const float* __restrict__ bias,
    float* __restrict__ C,
    int N, int K)
{
    __shared__ __align__(16) unsigned short As[3 * 4096];
    __shared__ __align__(16) unsigned short Bs[3 * 4096];
    int n0 = blockIdx.x * 128, m0 = blockIdx.y * 128;
    int tid = threadIdx.x;
    int lane = tid & 63, wv = tid >> 6;
    int wr = wv >> 1, wc = wv & 1;

    f32x4 acc[4][4] = {};

    int o0 = wv * 2048 + lane * 16;
    int row0 = o0 >> 6, sl0 = (o0 >> 4) & 3;
    int ib0 = (sl0 ^ ((row0 >> 1) & 3)) * 8;
    int o1 = o0 + 1024;
    int row1 = o1 >> 6, sl1 = (o1 >> 4) & 3;
    int ib1 = (sl1 ^ ((row1 >> 1) & 3)) * 8;

    auto stage = [&](int buf, int k0) {
        const unsigned short* ga0 = A + (size_t)(m0 + row0) * K + k0 + ib0;
        const unsigned short* gb0 = Bm + (size_t)(n0 + row0) * K + k0 + ib0;
        const unsigned short* ga1 = A + (size_t)(m0 + row1) * K + k0 + ib1;
        const unsigned short* gb1 = Bm + (size_t)(n0 + row1) * K + k0 + ib1;
        unsigned short* la0 = As + buf * 4096 + wv * 1024;
        unsigned short* lb0 = Bs + buf * 4096 + wv * 1024;
        __builtin_amdgcn_global_load_lds((const __attribute__((address_space(1))) void*)ga0,
                                         (__attribute__((address_space(3))) void*)la0, 16, 0, 0);
        __builtin_amdgcn_global_load_lds((const __attribute__((address_space(1))) void*)gb0,
                                         (__attribute__((address_space(3))) void*)lb0, 16, 0, 0);
        __builtin_amdgcn_global_load_lds((const __attribute__((address_space(1))) void*)ga1,
                                         (__attribute__((address_space(3))) void*)(la0 + 512), 16, 0, 0);
        __builtin_amdgcn_global_load_lds((const __attribute__((address_space(1))) void*)gb1,
                                         (__attribute__((address_space(3))) void*)(lb0 + 512), 16, 0, 0);
    };

    int rr2 = lane & 15, q = lane >> 4;
    int kqs = ((q ^ ((rr2 >> 1) & 3)) * 8);
    int rA = wr * 64 + rr2;
    int rB = wc * 64 + rr2;

    int NT = K >> 5;
    stage(0, 0);
    if (NT > 1) {
        stage(1, 32);
        asm volatile("s_waitcnt vmcnt(4)");
    } else {
        asm volatile("s_waitcnt vmcnt(0)");
    }
    __builtin_amdgcn_s_barrier();
    __builtin_amdgcn_sched_barrier(0);

    int cur = 0;
    for (int t = 0; t < NT; ++t) {
        if (t + 2 < NT) {
            int nb = cur + 2; if (nb >= 3) nb -= 3;
            stage(nb, (t + 2) << 5);
        }
        const unsigned short* ab = As + cur * 4096;
        const unsigned short* bb = Bs + cur * 4096;
        s16x8 af[4], bf[4];
#pragma unroll
        for (int i = 0; i < 4; ++i) {
            af[i] = *(const s16x8*)(ab + (rA + i * 16) * 32 + kqs);
            bf[i] = *(const s16x8*)(bb + (rB + i * 16) * 32 + kqs);
        }
#pragma unroll
        for (int mf = 0; mf < 4; ++mf)
#pragma unroll
            for (int nf = 0; nf < 4; ++nf)
                acc[mf][nf] = mfma16(af[mf], bf[nf], acc[mf][nf]);
        if (t + 1 < NT) {
            if (t + 2 < NT) asm volatile("s_waitcnt vmcnt(4)");
            else            asm volatile("s_waitcnt vmcnt(0)");
            asm volatile("s_waitcnt lgkmcnt(0)");
            __builtin_amdgcn_s_barrier();
            __builtin_amdgcn_sched_barrier(0);
        }
        cur = (cur == 2) ? 0 : cur + 1;
    }

#pragma unroll
    for (int nf = 0; nf < 4; ++nf) {
        int col = n0 + wc * 64 + nf * 16 + rr2;
        float bv = bias[col];
#pragma unroll
        for (int mf = 0; mf < 4; ++mf) {
            int mbase = m0 + wr * 64 + mf * 16 + q * 4;
#pragma unroll
            for (int r = 0; r < 4; ++r)
                C[(size_t)(mbase + r) * N + col] = acc[mf][nf][r] + bv;
        }
    }
}

// ---------------- logits GEMM: 256x256, BK=64, 8 waves, 4-phase counted-vmcnt ----------
// (R14-verified functionally correct: output 0 passed.)
__global__ __launch_bounds__(512) void gemm_logits(
    const unsigned short* __restrict__ A,     // hsb [2048,1024]
    const unsigned short* __restrict__ Bm,    // owb [32000,1024]
    const float* __restrict__ bias,           // out_b
    float* __restrict__ C,                    // out [2048,32000]
    float* __restrict__ pmax,                 // [2048,125]
    float* __restrict__ psum)                 // [2048,125]
{
    __shared__ __align__(16) unsigned short lds[65536];   // 128 KB
    __shared__ float spx[4][256], sps[4][256];            // 8 KB

    int m0 = blockIdx.x * 256;
    int ntile = blockIdx.y;
    int n0 = ntile * 256;
    int tid = threadIdx.x;
    int lane = tid & 63, wv = tid >> 6;
    int wr = wv >> 2, wc = wv & 3;          // 2M x 4N waves
    int q = lane >> 4, rr2 = lane & 15;
    int swz = rr2 & 7;

    int srow = tid >> 3;
    int scol = ((tid & 7) ^ (srow & 7)) * 8;

    f32x4 acc[8][4] = {};

    auto stage_unit = [&](int slot, const unsigned short* gb, int grow0, int kc) {
        const unsigned short* src = gb + (size_t)(grow0 + srow) * H_ + kc + scol;
        unsigned short* dst = lds + slot * 4096 + wv * 512;
        __builtin_amdgcn_global_load_lds((const __attribute__((address_space(1))) void*)src,
                                         (__attribute__((address_space(3))) void*)dst, 16, 0, 0);
    };

    stage_unit(0, Bm, n0,       0);
    stage_unit(1, Bm, n0 + 64,  0);
    stage_unit(2, Bm, n0 + 128, 0);
    stage_unit(3, Bm, n0 + 192, 0);
    stage_unit(4, A,  m0,       0);
    stage_unit(5, A,  m0 + 128, 0);
    stage_unit(6, A,  m0 + 64,  0);
    stage_unit(7, A,  m0 + 192, 0);

    for (int kt = 0; kt < NKT; ++kt) {
        int sb  = (kt & 1) ? 32768 : 0;
        int nsb = (kt & 1) ? 0 : 8;
        int A0 = sb + (4 + wr) * 4096;
        int A1 = sb + (6 + wr) * 4096;
        int Bb = sb + wc * 4096;
        int k1 = (kt + 1) << 6;
        bool more = (kt + 1 < NKT);

        s16x8 bf0[4], bf1[4], af[4];

        // ---- phase 0 ----
        asm volatile("s_waitcnt vmcnt(2)");
        __builtin_amdgcn_s_barrier();
        __builtin_amdgcn_sched_barrier(0);
        if (more) { stage_unit(nsb + 0, Bm, n0, k1); stage_unit(nsb + 1, Bm, n0 + 64, k1); }
#pragma unroll
        for (int i = 0; i < 4; ++i) {
            bf0[i] = *(const s16x8*)(lds + Bb + (i * 16 + rr2) * 64 + (q ^ swz) * 8);
            af[i]  = *(const s16x8*)(lds + A0 + (i * 16 + rr2) * 64 + (q ^ swz) * 8);
        }
        __builtin_amdgcn_s_setprio(1);
#pragma unroll
        for (int i = 0; i < 4; ++i)
#pragma unroll
            for (int nf = 0; nf < 4; ++nf)
                acc[i][nf] = mfma16(af[i], bf0[nf], acc[i][nf]);
        __builtin_amdgcn_s_setprio(0);

        // ---- phase 1 ----
        if (more) asm volatile("s_waitcnt vmcnt(2)");
        else      asm volatile("s_waitcnt vmcnt(0)");
        __builtin_amdgcn_s_barrier();
        __builtin_amdgcn_sched_barrier(0);
        if (more) { stage_unit(nsb + 2, Bm, n0 + 128, k1); stage_unit(nsb + 3, Bm, n0 + 192, k1); }
#pragma unroll
        for (int i = 0; i < 4; ++i)
            af[i] = *(const s16x8*)(lds + A1 + (i * 16 + rr2) * 64 + (q ^ swz) * 8);
        __builtin_amdgcn_s_setprio(1);
#pragma unroll
        for (int i = 0; i < 4; ++i)
#pragma unroll
            for (int nf = 0; nf < 4; ++nf)
                acc[4 + i][nf] = mfma16(af[i], bf0[nf], acc[4 + i][nf]);
        __builtin_amdgcn_s_setprio(0);

        // ---- phase 2 ----
        if (more) { stage_unit(nsb + 4, A, m0, k1); stage_unit(nsb + 5, A, m0 + 128, k1); }
#pragma unroll
        for (int i = 0; i < 4; ++i) {
            bf1[i] = *(const s16x8*)(lds + Bb + (i * 16 + rr2) * 64 + ((4 + q) ^ swz) * 8);
            af[i]  = *(const s16x8*)(lds + A0 + (i * 16 + rr2) * 64 + ((4 + q) ^ swz) * 8);
        }
        __builtin_amdgcn_s_setprio(1);
#pragma unroll
        for (int i = 0; i < 4; ++i)
#pragma unroll
            for (int nf = 0; nf < 4; ++nf)
                acc[i][nf] = mfma16(af[i], bf1[nf], acc[i][nf]);
        __builtin_amdgcn_s_setprio(0);

        // ---- phase 3 ----
        if (more) { stage_unit(nsb + 6, A, m0 + 64, k1); stage_unit(nsb + 7, A, m0 + 192, k1); }
#pragma unroll
        for (int i = 0; i < 4; ++i)
            af[i] = *(const s16x8*)(lds + A1 + (i * 16 + rr2) * 64 + ((4 + q) ^ swz) * 8);
        __builtin_amdgcn_s_setprio(1);
#pragma unroll
        for (int i = 0; i < 4; ++i)
#pragma unroll
            for (int nf = 0; nf < 4; ++nf)
                acc[4 + i][nf] = mfma16(af[i], bf1[nf], acc[4 + i][nf]);
        __builtin_amdgcn_s_setprio(0);
    }

    float bv[4];
#pragma unroll
    for (int nf = 0; nf < 4; ++nf) bv[nf] = bias[n0 + wc * 64 + nf * 16 + rr2];

#pragma unroll
    for (int mf = 0; mf < 8; ++mf) {
#pragma unroll
        for (int r = 0; r < 4; ++r) {
            int row_local = wr * 128 + mf * 16 + q * 4 + r;
            float vmax = -1e30f;
#pragma unroll
            for (int nf = 0; nf < 4; ++nf) vmax = fmaxf(vmax, acc[mf][nf][r] + bv[nf]);
#pragma unroll
            for (int o = 1; o < 16; o <<= 1) vmax = fmaxf(vmax, __shfl_xor(vmax, o));
            float vsum = 0.f;
#pragma unroll
            for (int nf = 0; nf < 4; ++nf) vsum += __expf(acc[mf][nf][r] + bv[nf] - vmax);
#pragma unroll
            for (int o = 1; o < 16; o <<= 1) vsum += __shfl_xor(vsum, o);
            if (rr2 == 0) { spx[wc][row_local] = vmax; sps[wc][row_local] = vsum; }
        }
    }

#pragma unroll
    for (int nf = 0; nf < 4; ++nf) {
        int col = n0 + wc * 64 + nf * 16 + rr2;
#pragma unroll
        for (int mf = 0; mf < 8; ++mf) {
            int mbase = m0 + wr * 128 + mf * 16 + q * 4;
#pragma unroll
            for (int r = 0; r < 4; ++r)
                C[(size_t)(mbase + r) * V_ + col] = acc[mf][nf][r] + bv[nf];
        }
    }

    __syncthreads();
    if (tid < 256) {
        int row = tid;
        float m0v = spx[0][row], m1v = spx[1][row], m2v = spx[2][row], m3v = spx[3][row];
        float Mv = fmaxf(fmaxf(m0v, m1v), fmaxf(m2v, m3v));
        float Sv = sps[0][row] * __expf(m0v - Mv) + sps[1][row] * __expf(m1v - Mv)
                 + sps[2][row] * __expf(m2v - Mv) + sps[3][row] * __expf(m3v - Mv);
        pmax[(size_t)(m0 + row) * NTN2 + ntile] = Mv;
        psum[(size_t)(m0 + row) * NTN2 + ntile] = Sv;
    }
}

// ---------------- persistent GRU scan (R13 structure; h published via ATOMIC exchange) ----
// Race fix (R16): an agent-scope atomic RMW must complete at the point of coherency, so
// its vmcnt-ack guarantees LLC-global visibility of h BEFORE the flag store issues
// (plain sc0sc1 store-ack may precede LLC visibility — suspected cause of the R14/R15
// intermittent staleness). Flags/hs/poll unchanged from the 9x-green protocol.
__global__ __launch_bounds__(256) void gru_scan(
    const unsigned short* __restrict__ Whhb,
    const float* __restrict__ b_hh,
    const float* __restrict__ enc_hidden,
    const float* __restrict__ xg,
    unsigned short* __restrict__ hb0, unsigned short* __restrict__ hb1,
    float* __restrict__ hfF,
    unsigned short* __restrict__ hs,
    unsigned int* __restrict__ flags)
{
    __shared__ __align__(16) unsigned short ws_[48 * 1024];
    __shared__ __align__(16) f32x4 red[2][3][64];

    int tid = threadIdx.x;
    int lane = tid & 63, wave = tid >> 6;
    int rt = wave >> 1, kh = wave & 1;
    int ct = blockIdx.x;

    for (int idx = tid; idx < 48 * 128; idx += 256) {
        int r = idx >> 7, slot = idx & 127;
        int g = r >> 4, jr = r & 15;
        s16x8 v = *(const s16x8*)(Whhb + (size_t)(g * H_ + ct * 16 + jr) * H_ + slot * 8);
        *(s16x8*)(ws_ + r * 1024 + (slot ^ (r & 7)) * 8) = v;
    }
    __syncthreads();

    int rr = lane & 15, q = lane >> 4;
    int col = ct * 16 + rr;
    int xsw = rr & 7;
    int kbase = kh * 512;
    int sbase = kh * 64 + q;
    float br = b_hh[col], bz = b_hh[H_ + col], bn = b_hh[2 * H_ + col];
    int b0 = rt * 16 + q * 4;

    float hold[4];
    float xr[4], xz[4], xn[4];
    if (kh == 1) {
#pragma unroll
        for (int r = 0; r < 4; ++r) {
            hold[r] = enc_hidden[(b0 + r) * H_ + col];
            const float* xrow = xg + ((size_t)(b0 + r) * T_) * G3;
            xr[r] = xrow[col]; xz[r] = xrow[H_ + col]; xn[r] = xrow[2 * H_ + col];
        }
    }

    for (int t = 0; t < T_; ++t) {
        const unsigned short* hbp = (t & 1) ? hb1 : hb0;
        unsigned short*       hbn = (t & 1) ? hb0 : hb1;

        const unsigned short* ha = hbp + (size_t)(rt * 16 + rr) * H_ + kbase + q * 8;
        s16x8 af[16];
#pragma unroll
        for (int i = 0; i < 16; ++i) af[i] = load_b128_cc(ha + i * 32);

        f32x4 accr, accz, accn;
        if (kh == 1) {
            accr = (f32x4){br, br, br, br};
            accz = (f32x4){bz, bz, bz, bz};
            accn = (f32x4){bn, bn, bn, bn};
        } else {
            accr = (f32x4){0.f, 0.f, 0.f, 0.f};
            accz = accr; accn = accr;
        }

        asm volatile("s_waitcnt vmcnt(0)");
        __builtin_amdgcn_sched_barrier(0);

#pragma unroll
        for (int kk = 0; kk < 16; ++kk) {
            int so = ((sbase + kk * 4) ^ xsw) * 8;
            s16x8 fr = *(const s16x8*)(ws_ + rr * 1024 + so);
            s16x8 fz = *(const s16x8*)(ws_ + (16 + rr) * 1024 + so);
            s16x8 fn = *(const s16x8*)(ws_ + (32 + rr) * 1024 + so);
            accr = mfma16(af[kk], fr, accr);
            accz = mfma16(af[kk], fz, accz);
            accn = mfma16(af[kk], fn, accn);
        }

        if (kh == 0) {
            red[rt][0][lane] = accr; red[rt][1][lane] = accz; red[rt][2][lane] = accn;
        }
        __syncthreads();
        if (kh == 1) {
            accr += red[rt][0][lane]; accz += red[rt][1][lane]; accn += red[rt][2][lane];
            unsigned int hpk[4];
#pragma unroll
            for (int r = 0; r < 4; ++r) {
                float rg = 1.f / (1.f + __expf(-(xr[r] + accr[r])));
                float zg = 1.f / (1.f + __expf(-(xz[r] + accz[r])));
                float ng = tanhf(xn[r] + rg * accn[r]);
                float hnew = (1.f - zg) * ng + zg * hold[r];
                hold[r] = hnew;
                hpk[r] = f2bf(hnew);
            }
#pragma unroll
            for (int r = 0; r < 4; ++r) {
                unsigned int other = __shfl_xor((int)hpk[r], 1);
                if ((rr & 1) == 0) {
                    unsigned int pk = hpk[r] | (other << 16);
                    // ATOMIC publish: completes at coherency point (see header comment)
                    unsigned int* dst = (unsigned int*)(hbn + (size_t)(b0 + r) * H_ + col);
                    (void)__hip_atomic_exchange(dst, pk, __ATOMIC_RELAXED, __HIP_MEMORY_SCOPE_AGENT);
                    *(unsigned int*)(hs + ((size_t)(b0 + r) * T_ + t) * H_ + col) = pk;   // plain (next-kernel consumer)
                }
            }
            if (t == T_ - 1) {
#pragma unroll
                for (int r = 0; r < 4; ++r) hfF[(b0 + r) * H_ + col] = hold[r];
            }
            asm volatile("s_waitcnt vmcnt(0)" ::: "memory");   // atomics ACK'd at LLC before flag
        }

        if (t < T_ - 1) {
            __syncthreads();
            if (tid == 0) store_b32_cc(flags + ct, (unsigned int)(t + 1));
            // xg prefetch for step t+1 (off the critical chain; issued before poll)
            if (kh == 1) {
#pragma unroll
                for (int r = 0; r < 4; ++r) {
                    const float* xrow = xg + ((size_t)(b0 + r) * T_ + (t + 1)) * G3;
                    xr[r] = xrow[col]; xz[r] = xrow[H_ + col]; xn[r] = xrow[2 * H_ + col];
                }
                __builtin_amdgcn_sched_barrier(0);
            }
            unsigned int tgt = (unsigned int)(t + 1);
            while (true) {
                unsigned int f = load_b32_cc(flags + lane);
                asm volatile("s_waitcnt vmcnt(0)");
                if (__all(f >= tgt)) break;
                __builtin_amdgcn_s_sleep(1);
            }
            __builtin_amdgcn_sched_barrier(0);
        }
    }
}

// ---------------- lse finalize + subtract + h-tail copy ----------------
__global__ __launch_bounds__(256) void lse_sub_copy(
    float* __restrict__ out,
    const float* __restrict__ pmax, const float* __restrict__ psum,
    const float* __restrict__ hfF)
{
    int m = blockIdx.x;
    int tid = threadIdx.x;
    __shared__ float sm[4], ssum[4];

    if (m < B_) {
        float4 v = *(const float4*)(hfF + m * H_ + tid * 4);
        *(float4*)(out + (size_t)M_ * V_ + m * H_ + tid * 4) = v;
    }

    float M = -1e30f, S = 0.f;
    for (int i = tid; i < NTN2; i += 256) {
        float pm_ = pmax[(size_t)m * NTN2 + i];
        float ps_ = psum[(size_t)m * NTN2 + i];
        float nm = fmaxf(M, pm_);
        S = S * __expf(M - nm) + ps_ * __expf(pm_ - nm);
        M = nm;
    }
    for (int o = 32; o > 0; o >>= 1) {
        float om = __shfl_xor(M, o), os = __shfl_xor(S, o);
        float nm = fmaxf(M, om);
        S = S * __expf(M - nm) + os * __expf(om - nm);
        M = nm;
    }
    int wv = tid >> 6, lane = tid & 63;
    if (lane == 0) { sm[wv] = M; ssum[wv] = S; }
    __syncthreads();
    float fm = fmaxf(fmaxf(sm[0], sm[1]), fmaxf(sm[2], sm[3]));
    float fs = ssum[0] * __expf(sm[0] - fm) + ssum[1] * __expf(sm[1] - fm)
             + ssum[2] * __expf(sm[2] - fm) + ssum[3] * __expf(sm[3] - fm);
    float lse = fm + __logf(fs);

    float* row = out + (size_t)m * V_;
    for (int i = tid * 4; i < V_; i += 1024) {
        float4 v = *(const float4*)(row + i);
        v.x -= lse; v.y -= lse; v.z -= lse; v.w -= lse;
        *(float4*)(row + i) = v;
    }
}

extern "C" void kernel_launch(void* const* d_in, const int* in_sizes, int n_in,
                              void* d_out, int out_size, void* d_ws, size_t ws_size,
                              hipStream_t stream) {
    const float* enc_hidden = (const float*)d_in[1];
    const int*   target     = (const int*)d_in[2];
    const float* embedding  = (const float*)d_in[3];
    const float* W_ih       = (const float*)d_in[4];
    const float* W_hh       = (const float*)d_in[5];
    const float* b_ih       = (const float*)d_in[6];
    const float* b_hh       = (const float*)d_in[7];
    const float* out_W      = (const float*)d_in[8];
    const float* out_b      = (const float*)d_in[9];
    float* out = (float*)d_out;

    char* ws = (char*)d_ws;
    float*          xg   = (float*)(ws);                         // [2048,3072] f32
    unsigned short* xb   = (unsigned short*)(ws + 25165824);     // [2048,1024] bf16 (pm reuse)
    unsigned short* hsb  = (unsigned short*)(ws + 29360128);     // [2048,1024] bf16
    unsigned short* wihb = (unsigned short*)(ws + 33554432);
    unsigned short* whhb = (unsigned short*)(ws + 39845888);
    unsigned short* owb  = (unsigned short*)(ws + 46137344);
    float*          hfF  = (float*)(ws + 111673344);
    unsigned short* hb0  = (unsigned short*)(ws + 111804416);
    unsigned short* hb1  = (unsigned short*)(ws + 111869952);
    unsigned int*   flg  = (unsigned int*)(ws + 111935488);
    float*          pmx  = (float*)(ws + 25165824);              // [2048,125]
    float*          psm  = (float*)(ws + 25165824 + 2048000);    // [2048,125]

    prep_all<<<2048, 256, 0, stream>>>(W_ih, W_hh, out_W, wihb, whhb, owb,
                                       target, embedding, xb, enc_hidden, hb0, flg);

    gemm_bias<<<dim3(G3 / 128, M_ / 128), 256, 0, stream>>>(xb, wihb, b_ih, xg, G3, H_);

    {
        void* args[] = { (void*)&whhb, (void*)&b_hh, (void*)&enc_hidden, (void*)&xg,
                         (void*)&hb0, (void*)&hb1, (void*)&hfF, (void*)&hsb, (void*)&flg };
        hipLaunchCooperativeKernel((const void*)gru_scan, dim3(NB_SCAN), dim3(256), args, 0, stream);
    }

    gemm_logits<<<dim3(M_ / 256, NTN2), 512, 0, stream>>>(hsb, owb, out_b, out, pmx, psm);

    lse_sub_copy<<<M_, 256, 0, stream>>>(out, pmx, psm, hfF);
}